// Round 1
// baseline (242.245 us; speedup 1.0000x reference)
//
#include <hip/hip_runtime.h>
#include <math.h>

#define NPTS  4096
#define BATCH 8
#define BLOCK 256

// dir 0: for each x[n], min over y[m]; dir 1: for each y[n], min over x[m].
// Per (batch, dir): block-tile the n axis; stage the full opposing set in LDS.
__global__ __launch_bounds__(BLOCK) void maxmin_kernel(
    const float* __restrict__ x, const float* __restrict__ y,
    float* __restrict__ ws) {
  const int b   = blockIdx.y;
  const int dir = blockIdx.z;

  const float* __restrict__ P = (dir == 0) ? x : y;  // points we scan (n)
  const float* __restrict__ Q = (dir == 0) ? y : x;  // set we min over (m)
  const float* Pb = P + (size_t)b * NPTS * 3;
  const float* Qb = Q + (size_t)b * NPTS * 3;

  __shared__ float qx[NPTS];
  __shared__ float qy[NPTS];
  __shared__ float qz[NPTS];

  for (int m = threadIdx.x; m < NPTS; m += BLOCK) {
    qx[m] = Qb[3 * m + 0];
    qy[m] = Qb[3 * m + 1];
    qz[m] = Qb[3 * m + 2];
  }
  __syncthreads();

  const int n = blockIdx.x * BLOCK + threadIdx.x;
  const float px = Pb[3 * n + 0];
  const float py = Pb[3 * n + 1];
  const float pz = Pb[3 * n + 2];

  float mn = 3.4e38f;
#pragma unroll 8
  for (int m = 0; m < NPTS; ++m) {
    float dx = px - qx[m];
    float dy = py - qy[m];
    float dz = pz - qz[m];
    float d2 = dx * dx + dy * dy + dz * dz;
    mn = fminf(mn, d2);
  }

  // max over the block (each thread holds min_m for its n)
  for (int off = 32; off > 0; off >>= 1)
    mn = fmaxf(mn, __shfl_down(mn, off));

  __shared__ float wmax[BLOCK / 64];
  if ((threadIdx.x & 63) == 0) wmax[threadIdx.x >> 6] = mn;
  __syncthreads();

  if (threadIdx.x == 0) {
    float bm = wmax[0];
#pragma unroll
    for (int i = 1; i < BLOCK / 64; ++i) bm = fmaxf(bm, wmax[i]);
    // d2 >= 0 so float ordering == uint-bit ordering; ws pre-zeroed.
    atomicMax((unsigned int*)&ws[dir * BATCH + b], __float_as_uint(bm));
  }
}

__global__ void finalize_kernel(const float* __restrict__ ws,
                                float* __restrict__ out) {
  if (threadIdx.x == 0) {
    float s = 0.0f;
#pragma unroll
    for (int b = 0; b < BATCH; ++b) {
      float m = fmaxf(ws[b], ws[BATCH + b]);  // max of the two directed d2-maxmins
      s += sqrtf(m);
    }
    out[0] = s / (float)BATCH;
  }
}

extern "C" void kernel_launch(void* const* d_in, const int* in_sizes, int n_in,
                              void* d_out, int out_size, void* d_ws, size_t ws_size,
                              hipStream_t stream) {
  const float* x = (const float*)d_in[0];
  const float* y = (const float*)d_in[1];
  float* ws = (float*)d_ws;
  float* out = (float*)d_out;

  hipMemsetAsync(ws, 0, 2 * BATCH * sizeof(float), stream);

  dim3 grid(NPTS / BLOCK, BATCH, 2);
  maxmin_kernel<<<grid, BLOCK, 0, stream>>>(x, y, ws);
  finalize_kernel<<<1, 64, 0, stream>>>(ws, out);
}

// Round 2
// 95.070 us; speedup vs baseline: 2.5481x; 2.5481x over previous
//
#include <hip/hip_runtime.h>
#include <math.h>

#define NPTS   4096
#define BATCH  8
#define BLOCK  256
#define PN     4                 // p points per thread
#define MCHUNK 256               // q points staged per block
#define NTILE  (BLOCK * PN)      // 1024 n per block

// Pass 1: partial min over one m-chunk for 1024 n's; combine via atomicMin.
// bd = b*2 + dir. dir 0: p=x, q=y; dir 1: p=y, q=x.
__global__ __launch_bounds__(BLOCK) void partial_min_kernel(
    const float* __restrict__ x, const float* __restrict__ y,
    unsigned int* __restrict__ wsmin) {
  const int bd  = blockIdx.z;
  const int b   = bd >> 1;
  const int dir = bd & 1;

  const float* __restrict__ P = (dir == 0) ? x : y;
  const float* __restrict__ Q = (dir == 0) ? y : x;
  const float* Pb = P + (size_t)b * NPTS * 3;
  const float* Qb = Q + (size_t)b * NPTS * 3 + (size_t)blockIdx.y * MCHUNK * 3;

  __shared__ float4 q[MCHUNK];
  {
    const int m = threadIdx.x;  // MCHUNK == BLOCK
    q[m] = make_float4(Qb[3 * m + 0], Qb[3 * m + 1], Qb[3 * m + 2], 0.0f);
  }
  __syncthreads();

  const int n0 = blockIdx.x * NTILE + threadIdx.x;
  float px[PN], py[PN], pz[PN], mn[PN];
#pragma unroll
  for (int i = 0; i < PN; ++i) {
    const int n = n0 + i * BLOCK;
    px[i] = Pb[3 * n + 0];
    py[i] = Pb[3 * n + 1];
    pz[i] = Pb[3 * n + 2];
    mn[i] = 3.4e38f;
  }

#pragma unroll 4
  for (int m = 0; m < MCHUNK; ++m) {
    const float4 qq = q[m];  // uniform address -> broadcast ds_read_b128
#pragma unroll
    for (int i = 0; i < PN; ++i) {
      const float dx = px[i] - qq.x;
      const float dy = py[i] - qq.y;
      const float dz = pz[i] - qq.z;
      const float d2 = dx * dx + dy * dy + dz * dz;
      mn[i] = fminf(mn[i], d2);
    }
  }

  unsigned int* wm = wsmin + (size_t)bd * NPTS;
#pragma unroll
  for (int i = 0; i < PN; ++i)
    atomicMin(&wm[n0 + i * BLOCK], __float_as_uint(mn[i]));
}

// Pass 2: per batch, max over both directed min-arrays (8192 vals), sqrt, mean.
__global__ __launch_bounds__(256) void reduce_kernel(
    const unsigned int* __restrict__ wsmin, float* __restrict__ out) {
  __shared__ float wmax[4];
  float s = 0.0f;
  for (int b = 0; b < BATCH; ++b) {
    const unsigned int* base = wsmin + (size_t)b * 2 * NPTS;
    float mx = 0.0f;
    for (int i = threadIdx.x; i < 2 * NPTS; i += 256)
      mx = fmaxf(mx, __uint_as_float(base[i]));
    for (int off = 32; off > 0; off >>= 1)
      mx = fmaxf(mx, __shfl_down(mx, off));
    if ((threadIdx.x & 63) == 0) wmax[threadIdx.x >> 6] = mx;
    __syncthreads();
    if (threadIdx.x == 0) {
      const float m = fmaxf(fmaxf(wmax[0], wmax[1]), fmaxf(wmax[2], wmax[3]));
      s += sqrtf(m);
    }
    __syncthreads();
  }
  if (threadIdx.x == 0) out[0] = s / (float)BATCH;
}

extern "C" void kernel_launch(void* const* d_in, const int* in_sizes, int n_in,
                              void* d_out, int out_size, void* d_ws, size_t ws_size,
                              hipStream_t stream) {
  const float* x = (const float*)d_in[0];
  const float* y = (const float*)d_in[1];
  unsigned int* wsmin = (unsigned int*)d_ws;
  float* out = (float*)d_out;

  // Init partial-min array to 0xFFFFFFFF (uint-max; any d2 bits are smaller).
  hipMemsetAsync(wsmin, 0xFF, (size_t)2 * BATCH * NPTS * sizeof(unsigned int), stream);

  dim3 grid(NPTS / NTILE, NPTS / MCHUNK, 2 * BATCH);  // (4, 16, 16)
  partial_min_kernel<<<grid, BLOCK, 0, stream>>>(x, y, wsmin);
  reduce_kernel<<<1, 256, 0, stream>>>(wsmin, out);
}

// Round 3
// 42.817 us; speedup vs baseline: 5.6577x; 2.2204x over previous
//
#include <hip/hip_runtime.h>
#include <math.h>

#define NPTS   4096
#define BATCH  8
#define BLOCK  256
#define PN     4                 // p points per thread
#define MCHUNK 256               // q points staged per block (128 pairs)
#define NTILE  (BLOCK * PN)      // 1024 n per block

typedef float v2f __attribute__((ext_vector_type(2)));

static __device__ __forceinline__ v2f pk_fma(v2f a, v2f b, v2f c) {
  v2f d;
  asm("v_pk_fma_f32 %0, %1, %2, %3" : "=v"(d) : "v"(a), "v"(b), "v"(c));
  return d;
}

// Monotone float -> uint key (order-preserving incl. negatives).
static __device__ __forceinline__ unsigned int fkey(float f) {
  unsigned int u = __float_as_uint(f);
  return (u & 0x80000000u) ? ~u : (u | 0x80000000u);
}
static __device__ __forceinline__ float funkey(unsigned int k) {
  return __uint_as_float((k & 0x80000000u) ? (k ^ 0x80000000u) : ~k);
}

// Pass 1: per (bd, m-chunk, n-tile), partial min over the chunk of
// t = |q|^2 - 2 p.q, plus |p|^2; combine across chunks via atomicMin on keys.
// bd = b*2 + dir. dir 0: p=x, q=y; dir 1: p=y, q=x.
__global__ __launch_bounds__(BLOCK) void partial_min_kernel(
    const float* __restrict__ x, const float* __restrict__ y,
    unsigned int* __restrict__ wsmin) {
  const int bd  = blockIdx.z;
  const int b   = bd >> 1;
  const int dir = bd & 1;

  const float* __restrict__ P = (dir == 0) ? x : y;
  const float* __restrict__ Q = (dir == 0) ? y : x;
  const float* Pb = P + (size_t)b * NPTS * 3;
  const float* Qb = Q + (size_t)b * NPTS * 3 + (size_t)blockIdx.y * MCHUNK * 3;

  // Per q-pair (2 points): qA = (-2x0,-2x1,-2y0,-2y1), qB = (-2z0,-2z1,|q0|^2,|q1|^2)
  __shared__ float4 qA[MCHUNK / 2];
  __shared__ float4 qB[MCHUNK / 2];
  if (threadIdx.x < MCHUNK / 2) {
    const int t = threadIdx.x;
    const float x0 = Qb[6 * t + 0], y0 = Qb[6 * t + 1], z0 = Qb[6 * t + 2];
    const float x1 = Qb[6 * t + 3], y1 = Qb[6 * t + 4], z1 = Qb[6 * t + 5];
    qA[t] = make_float4(-2.0f * x0, -2.0f * x1, -2.0f * y0, -2.0f * y1);
    qB[t] = make_float4(-2.0f * z0, -2.0f * z1,
                        x0 * x0 + y0 * y0 + z0 * z0,
                        x1 * x1 + y1 * y1 + z1 * z1);
  }
  __syncthreads();

  const int n0 = blockIdx.x * NTILE + threadIdx.x;
  v2f px2[PN], py2[PN], pz2[PN];
  float p2[PN], mn[PN];
#pragma unroll
  for (int i = 0; i < PN; ++i) {
    const int n = n0 + i * BLOCK;
    const float px = Pb[3 * n + 0];
    const float py = Pb[3 * n + 1];
    const float pz = Pb[3 * n + 2];
    px2[i] = (v2f){px, px};
    py2[i] = (v2f){py, py};
    pz2[i] = (v2f){pz, pz};
    p2[i]  = px * px + py * py + pz * pz;
    mn[i]  = 3.4e38f;
  }

#pragma unroll 4
  for (int m = 0; m < MCHUNK / 2; ++m) {
    const float4 a = qA[m];  // uniform address -> broadcast ds_read_b128
    const float4 c = qB[m];
    const v2f qx = (v2f){a.x, a.y};
    const v2f qy = (v2f){a.z, a.w};
    const v2f qz = (v2f){c.x, c.y};
    const v2f qw = (v2f){c.z, c.w};
#pragma unroll
    for (int i = 0; i < PN; ++i) {
      v2f t = pk_fma(pz2[i], qz, qw);
      t = pk_fma(py2[i], qy, t);
      t = pk_fma(px2[i], qx, t);
      mn[i] = fminf(mn[i], fminf(t.x, t.y));  // -> v_min3_f32
    }
  }

  unsigned int* wm = wsmin + (size_t)bd * NPTS;
#pragma unroll
  for (int i = 0; i < PN; ++i)
    atomicMin(&wm[n0 + i * BLOCK], fkey(mn[i] + p2[i]));
}

// Pass 2 (single block, 16 waves): wave w maxes the 4096 keys of bd=w,
// then wave 0 combines directions, sqrt, mean.
__global__ __launch_bounds__(1024) void reduce_kernel(
    const unsigned int* __restrict__ wsmin, float* __restrict__ out) {
  const int wid  = threadIdx.x >> 6;   // = bd
  const int lane = threadIdx.x & 63;
  const unsigned int* base = wsmin + (size_t)wid * NPTS;

  unsigned int mk = 0;
  for (int k = lane; k < NPTS; k += 64) mk = max(mk, base[k]);
  for (int off = 32; off > 0; off >>= 1)
    mk = max(mk, (unsigned int)__shfl_down(mk, off));

  __shared__ float d2s[2 * BATCH];
  if (lane == 0) d2s[wid] = fmaxf(funkey(mk), 0.0f);  // clamp >= 0
  __syncthreads();

  if (threadIdx.x == 0) {
    float s = 0.0f;
#pragma unroll
    for (int b = 0; b < BATCH; ++b)
      s += sqrtf(fmaxf(d2s[2 * b], d2s[2 * b + 1]));
    out[0] = s / (float)BATCH;
  }
}

extern "C" void kernel_launch(void* const* d_in, const int* in_sizes, int n_in,
                              void* d_out, int out_size, void* d_ws, size_t ws_size,
                              hipStream_t stream) {
  const float* x = (const float*)d_in[0];
  const float* y = (const float*)d_in[1];
  unsigned int* wsmin = (unsigned int*)d_ws;
  float* out = (float*)d_out;

  // 0xFFFFFFFF is the max key -> identity for key-atomicMin.
  hipMemsetAsync(wsmin, 0xFF, (size_t)2 * BATCH * NPTS * sizeof(unsigned int), stream);

  dim3 grid(NPTS / NTILE, NPTS / MCHUNK, 2 * BATCH);  // (4, 16, 16)
  partial_min_kernel<<<grid, BLOCK, 0, stream>>>(x, y, wsmin);
  reduce_kernel<<<1, 1024, 0, stream>>>(wsmin, out);
}